// Round 1
// baseline (321.923 us; speedup 1.0000x reference)
//
#include <hip/hip_runtime.h>

// Problem constants
#define HEADS 16
#define DH    64      // head dim
#define EMB   1024
#define NBAT  2
#define SEQ   2048    // S == T
#define KDIM  1024

typedef __attribute__((ext_vector_type(8))) short short8;   // 8 bf16 (4 VGPR) MFMA A/B frag
typedef __attribute__((ext_vector_type(4))) float floatx4;  // MFMA C/D frag
typedef unsigned short u16;
typedef unsigned int   u32;

__device__ __forceinline__ u16 f2bf(float x) {          // fp32 -> bf16 RNE
    u32 u = __builtin_bit_cast(u32, x);
    u += 0x7fffu + ((u >> 16) & 1u);
    return (u16)(u >> 16);
}
__device__ __forceinline__ float bf2f(u16 v) {
    return __builtin_bit_cast(float, ((u32)v) << 16);
}

// ---------------------------------------------------------------------------
// Projection GEMM: out = X @ W^T + b, X [4096,1024] fp32, W [1024,1024] fp32.
// 128x128 tile / workgroup, 4 waves each 64x64 (4x4 of 16x16x32 bf16 MFMA).
// z=0: Q -> qh[n][h][s][d] bf16; z=1: K -> kh[n][h][t][d]; z=2: V -> vt[n][h][d][t] (transposed).
// ---------------------------------------------------------------------------
__global__ __launch_bounds__(256) void proj_kernel(
    const float* __restrict__ qin, const float* __restrict__ kin, const float* __restrict__ vin,
    const float* __restrict__ Wq,  const float* __restrict__ Wk,  const float* __restrict__ Wv,
    const float* __restrict__ bq,  const float* __restrict__ bk,  const float* __restrict__ bv,
    u16* __restrict__ qh, u16* __restrict__ kh, u16* __restrict__ vt)
{
    const int z = blockIdx.z;
    const float* X  = (z == 0) ? qin : (z == 1) ? kin : vin;
    const float* W  = (z == 0) ? Wq  : (z == 1) ? Wk  : Wv;
    const float* Bp = (z == 0) ? bq  : (z == 1) ? bk  : bv;
    u16* dst        = (z == 0) ? qh  : (z == 1) ? kh  : vt;

    const int m0 = blockIdx.y * 128;
    const int n0 = blockIdx.x * 128;
    const int tid  = threadIdx.x;
    const int wave = tid >> 6, lane = tid & 63;
    const int quad = lane >> 4, l15 = lane & 15;
    const int waveM = wave >> 1, waveN = wave & 1;

    // row stride 40 bf16 = 80B: 16B-aligned rows, 2-way bank aliasing (free)
    __shared__ __align__(16) u16 As[128 * 40];
    __shared__ __align__(16) u16 Bs[128 * 40];

    floatx4 acc[4][4];
    for (int a = 0; a < 4; a++)
        for (int b = 0; b < 4; b++)
            for (int r = 0; r < 4; r++) acc[a][b][r] = 0.f;

    for (int k0 = 0; k0 < KDIM; k0 += 32) {
        // stage 128x32 fp32 -> bf16 for A and B tiles (4 float4 per thread each)
        for (int i = 0; i < 4; i++) {
            int idx = i * 256 + tid;
            int row = idx >> 3, c4 = idx & 7;
            float4 a = *(const float4*)(X + (size_t)(m0 + row) * KDIM + k0 + c4 * 4);
            float4 b = *(const float4*)(W + (size_t)(n0 + row) * KDIM + k0 + c4 * 4);
            uint2 pa, pb;
            pa.x = (u32)f2bf(a.x) | ((u32)f2bf(a.y) << 16);
            pa.y = (u32)f2bf(a.z) | ((u32)f2bf(a.w) << 16);
            pb.x = (u32)f2bf(b.x) | ((u32)f2bf(b.y) << 16);
            pb.y = (u32)f2bf(b.z) | ((u32)f2bf(b.w) << 16);
            *(uint2*)&As[row * 40 + c4 * 4] = pa;
            *(uint2*)&Bs[row * 40 + c4 * 4] = pb;
        }
        __syncthreads();

        short8 af[4], bfg[4];
        for (int mb = 0; mb < 4; mb++)
            af[mb]  = *(const short8*)&As[(waveM * 64 + mb * 16 + l15) * 40 + quad * 8];
        for (int nb = 0; nb < 4; nb++)
            bfg[nb] = *(const short8*)&Bs[(waveN * 64 + nb * 16 + l15) * 40 + quad * 8];
        for (int mb = 0; mb < 4; mb++)
            for (int nb = 0; nb < 4; nb++)
                acc[mb][nb] = __builtin_amdgcn_mfma_f32_16x16x32_bf16(af[mb], bfg[nb], acc[mb][nb], 0, 0, 0);
        __syncthreads();
    }

    // epilogue: bias + store bf16 in head-split layout
    const int row0 = m0 + waveM * 64;
    const int col0 = n0 + waveN * 64;
    for (int nb = 0; nb < 4; nb++) {
        int col = col0 + nb * 16 + l15;            // output embedding index
        float bias = Bp[col];
        int hh = col >> 6, dd = col & 63;
        for (int mb = 0; mb < 4; mb++) {
            for (int r = 0; r < 4; r++) {
                int row = row0 + mb * 16 + quad * 4 + r;   // C/D: row = quad*4+reg (m89)
                int nn = row >> 11, ss = row & 2047;
                u16 o = f2bf(acc[mb][nb][r] + bias);
                if (z == 2)
                    dst[((size_t)(nn * HEADS + hh) * DH + dd) * SEQ + ss];   // placeholder removed below
                if (z == 2)
                    dst[((size_t)(nn * HEADS + hh) * DH + dd) * SEQ + ss] = o;  // V^T [n][h][d][t]
                else
                    dst[((size_t)(nn * HEADS + hh) * SEQ + ss) * DH + dd] = o;  // [n][h][s][d]
            }
        }
    }
}

// ---------------------------------------------------------------------------
// vmean[n*H*D + h*D + d] = mean over t of V  (for fully-masked-row fallback)
// ---------------------------------------------------------------------------
__global__ __launch_bounds__(256) void vmean_kernel(const u16* __restrict__ vt,
                                                    float* __restrict__ vmean)
{
    const int row = blockIdx.x;                // (n*H + h)*D + d
    const u16* p = vt + (size_t)row * SEQ;
    const int tid = threadIdx.x;
    float s = 0.f;
    for (int i = tid; i < SEQ; i += 256) s += bf2f(p[i]);
    __shared__ float red[256];
    red[tid] = s;
    __syncthreads();
    for (int st = 128; st > 0; st >>= 1) {
        if (tid < st) red[tid] += red[tid + st];
        __syncthreads();
    }
    if (tid == 0) vmean[row] = red[0] * (1.f / (float)SEQ);
}

// ---------------------------------------------------------------------------
// Flash-style attention, no max-subtraction (scores are O(10): exp fits fp32).
// Workgroup: one (n,h) x 128-row Q block. 4 waves x 32 rows. t-blocks of 64.
// l (row sum) accumulated via MFMA against a ones-fragment -> no shuffles.
// Degenerate rows (l==0, i.e. all t<=s pad-masked) get vmean (reference:
// softmax over all -1e9 == uniform over all T keys == mean(V)).
// ---------------------------------------------------------------------------
__global__ __launch_bounds__(256) void attn_kernel(
    const u16* __restrict__ qh, const u16* __restrict__ kh, const u16* __restrict__ vt,
    const int* __restrict__ pad, const float* __restrict__ vmean,
    float* __restrict__ out)
{
    const int nh = blockIdx.y;                 // n*H + h
    const int n = nh >> 4, h = nh & 15;
    const int s0 = blockIdx.x * 128;
    const int tid  = threadIdx.x;
    const int wave = tid >> 6, lane = tid & 63;
    const int quad = lane >> 4, l15 = lane & 15;

    __shared__ __align__(16) u16 Ks[64 * 72];   // K tile [t][d], stride 72
    __shared__ __align__(16) u16 Vs[64 * 72];   // V^T tile [d][t]
    __shared__ __align__(16) u16 Ps[128 * 72];  // P round-trip C-layout -> A-layout
    __shared__ int pads[SEQ];

    for (int i = tid; i < SEQ; i += 256) pads[i] = pad[n * SEQ + i];

    // Q fragments in registers: rows s0+wave*32+mb*16+l15, k = ks*32+quad*8
    const u16* qbase = qh + (size_t)nh * SEQ * DH;
    short8 qf[2][2];
    for (int mb = 0; mb < 2; mb++)
        for (int ks = 0; ks < 2; ks++)
            qf[mb][ks] = *(const short8*)(qbase + (size_t)(s0 + wave * 32 + mb * 16 + l15) * DH + ks * 32 + quad * 8);

    floatx4 oacc[2][4], lacc[2];
    for (int mb = 0; mb < 2; mb++) {
        for (int nd = 0; nd < 4; nd++)
            for (int r = 0; r < 4; r++) oacc[mb][nd][r] = 0.f;
        for (int r = 0; r < 4; r++) lacc[mb][r] = 0.f;
    }

    short8 ones;
    for (int i = 0; i < 8; i++) ones[i] = (short)0x3F80;   // bf16(1.0)

    const u16* kbase = kh + (size_t)nh * SEQ * DH;
    const u16* vbase = vt + (size_t)nh * DH * SEQ;
    const int nt = (s0 >> 6) + 2;              // causal: visit t-blocks up to diagonal

    __syncthreads();                           // pads staged

    for (int tb = 0; tb < nt; tb++) {
        const int t0 = tb * 64;
        // stage K [64t][64d] and V^T [64d][64t] (2 x 16B chunks per thread each)
        for (int i = 0; i < 2; i++) {
            int idx = i * 256 + tid;
            int row = idx >> 3, c = idx & 7;
            *(short8*)&Ks[row * 72 + c * 8] = *(const short8*)(kbase + (size_t)(t0 + row) * DH + c * 8);
            *(short8*)&Vs[row * 72 + c * 8] = *(const short8*)(vbase + (size_t)row * SEQ + t0 + c * 8);
        }
        __syncthreads();

        // scores: S = Q K^T  (per wave: 32 rows x 64 t-cols)
        floatx4 sc[2][4];
        for (int mb = 0; mb < 2; mb++)
            for (int nb = 0; nb < 4; nb++)
                for (int r = 0; r < 4; r++) sc[mb][nb][r] = 0.f;
        for (int ks = 0; ks < 2; ks++) {
            short8 bfg[4];
            for (int nb = 0; nb < 4; nb++)
                bfg[nb] = *(const short8*)&Ks[(nb * 16 + l15) * 72 + ks * 32 + quad * 8];
            for (int mb = 0; mb < 2; mb++)
                for (int nb = 0; nb < 4; nb++)
                    sc[mb][nb] = __builtin_amdgcn_mfma_f32_16x16x32_bf16(qf[mb][ks], bfg[nb], sc[mb][nb], 0, 0, 0);
        }

        // mask + exp + write P (bf16) to LDS in C-layout positions
        for (int mb = 0; mb < 2; mb++) {
            int srow_base = s0 + wave * 32 + mb * 16 + quad * 4;
            int prow_base = wave * 32 + mb * 16 + quad * 4;
            for (int nb = 0; nb < 4; nb++) {
                int tcol = t0 + nb * 16 + l15;
                bool ok = (pads[tcol] != 0);
                for (int r = 0; r < 4; r++) {
                    float p = (ok && tcol <= srow_base + r) ? __expf(sc[mb][nb][r] * 0.125f) : 0.f;
                    Ps[(prow_base + r) * 72 + nb * 16 + l15] = f2bf(p);
                }
            }
        }
        __syncthreads();

        // PV: O += P V ; l += P @ ones  (A-layout read of P: m=l15, k=quad*8+j)
        for (int ks = 0; ks < 2; ks++) {
            short8 pa[2];
            for (int mb = 0; mb < 2; mb++)
                pa[mb] = *(const short8*)&Ps[(wave * 32 + mb * 16 + l15) * 72 + ks * 32 + quad * 8];
            short8 vb[4];
            for (int nd = 0; nd < 4; nd++)
                vb[nd] = *(const short8*)&Vs[(nd * 16 + l15) * 72 + ks * 32 + quad * 8];
            for (int mb = 0; mb < 2; mb++) {
                for (int nd = 0; nd < 4; nd++)
                    oacc[mb][nd] = __builtin_amdgcn_mfma_f32_16x16x32_bf16(pa[mb], vb[nd], oacc[mb][nd], 0, 0, 0);
                lacc[mb] = __builtin_amdgcn_mfma_f32_16x16x32_bf16(pa[mb], ones, lacc[mb], 0, 0, 0);
            }
        }
        __syncthreads();
    }

    // epilogue: out = O / l ; degenerate rows (l==0) -> vmean
    float vm[4];
    for (int nd = 0; nd < 4; nd++) vm[nd] = vmean[nh * DH + nd * 16 + l15];
    for (int mb = 0; mb < 2; mb++) {
        for (int r = 0; r < 4; r++) {
            float l = lacc[mb][r];
            int srow = s0 + wave * 32 + mb * 16 + quad * 4 + r;
            float* orow = out + (size_t)(n * SEQ + srow) * EMB + h * DH;
            if (l > 0.f) {
                float inv = 1.f / l;
                for (int nd = 0; nd < 4; nd++) orow[nd * 16 + l15] = oacc[mb][nd][r] * inv;
            } else {
                for (int nd = 0; nd < 4; nd++) orow[nd * 16 + l15] = vm[nd];
            }
        }
    }
}

extern "C" void kernel_launch(void* const* d_in, const int* in_sizes, int n_in,
                              void* d_out, int out_size, void* d_ws, size_t ws_size,
                              hipStream_t stream)
{
    const float* qin = (const float*)d_in[0];
    const float* kin = (const float*)d_in[1];
    const float* vin = (const float*)d_in[2];
    const int*   pad = (const int*)d_in[3];
    // d_in[4] = subsq_mask (tril) — implemented analytically as t <= s
    const float* Wq = (const float*)d_in[5];
    const float* bq = (const float*)d_in[6];
    const float* Wk = (const float*)d_in[7];
    const float* bk = (const float*)d_in[8];
    const float* Wv = (const float*)d_in[9];
    const float* bv = (const float*)d_in[10];
    float* out = (float*)d_out;

    const size_t per = (size_t)NBAT * HEADS * SEQ * DH;  // 4M bf16 elements
    u16* qh = (u16*)d_ws;
    u16* kh = qh + per;
    u16* vt = kh + per;
    float* vmean = (float*)(vt + per);                   // 2048 floats

    proj_kernel<<<dim3(EMB / 128, (NBAT * SEQ) / 128, 3), 256, 0, stream>>>(
        qin, kin, vin, Wq, Wk, Wv, bq, bk, bv, qh, kh, vt);
    vmean_kernel<<<dim3(NBAT * HEADS * DH), 256, 0, stream>>>(vt, vmean);
    attn_kernel<<<dim3(SEQ / 128, NBAT * HEADS), 256, 0, stream>>>(qh, kh, vt, pad, vmean, out);
}

// Round 2
// 242.753 us; speedup vs baseline: 1.3261x; 1.3261x over previous
//
#include <hip/hip_runtime.h>

#define HEADS 16
#define DH    64
#define EMB   1024
#define NBAT  2
#define SEQ   2048
#define KDIM  1024
#define NROW  (NBAT * SEQ)     // 4096 rows in projection GEMM

typedef __attribute__((ext_vector_type(8))) short short8;   // 8 bf16 MFMA A/B frag
typedef __attribute__((ext_vector_type(4))) short short4v;  // 4 bf16 (8B packed store)
typedef __attribute__((ext_vector_type(4))) float floatx4;  // MFMA C/D frag
typedef unsigned short u16;
typedef unsigned int   u32;

__device__ __forceinline__ u16 f2bf(float x) {          // fp32 -> bf16 RNE
    u32 u = __builtin_bit_cast(u32, x);
    u += 0x7fffu + ((u >> 16) & 1u);
    return (u16)(u >> 16);
}
__device__ __forceinline__ float bf2f(u16 v) {
    return __builtin_bit_cast(float, ((u32)v) << 16);
}

// async global->LDS, 16B per lane; LDS dest must be wave-uniform base (lane scatters +lane*16)
__device__ __forceinline__ void gll16(const u16* g, u16* l) {
    __builtin_amdgcn_global_load_lds((const __attribute__((address_space(1))) u32*)g,
                                     (__attribute__((address_space(3))) u32*)l, 16, 0, 0);
}

// ---------------------------------------------------------------------------
// fp32 -> bf16 pre-convert of X (q,k,v: 4M elems each) and W (wq,wk,wv: 1M each)
// ---------------------------------------------------------------------------
__global__ __launch_bounds__(256) void cvt_kernel(
    const float* __restrict__ q, const float* __restrict__ k, const float* __restrict__ v,
    const float* __restrict__ wq, const float* __restrict__ wk, const float* __restrict__ wv,
    u16* __restrict__ xb, u16* __restrict__ wb)
{
    const int z = blockIdx.y;
    const float* src; u16* dst; int n;
    if (z < 3) { src = (z == 0) ? q : (z == 1) ? k : v;     dst = xb + (size_t)z * 4194304;       n = 4194304; }
    else       { src = (z == 3) ? wq : (z == 4) ? wk : wv;  dst = wb + (size_t)(z - 3) * 1048576; n = 1048576; }
    for (int i = (blockIdx.x * 256 + threadIdx.x) * 8; i < n; i += 512 * 256 * 8) {
        float4 a = *(const float4*)(src + i);
        float4 b = *(const float4*)(src + i + 4);
        short8 o;
        o[0] = (short)f2bf(a.x); o[1] = (short)f2bf(a.y); o[2] = (short)f2bf(a.z); o[3] = (short)f2bf(a.w);
        o[4] = (short)f2bf(b.x); o[5] = (short)f2bf(b.y); o[6] = (short)f2bf(b.z); o[7] = (short)f2bf(b.w);
        *(short8*)(dst + i) = o;
    }
}

// ---------------------------------------------------------------------------
// bf16 GEMM: out = Xb @ Wb^T (+bias), m97 structure: 128x128 tile, BK=64,
// global_load_lds width-16 staging, 4 waves x (4x4 of 16x16x32 MFMA).
// z=0: Q*0.125 -> qh[n][h][s][d]; z=1: K -> kh[n][h][t][d]; z=2: V -> vt[n][h][d][t].
// ---------------------------------------------------------------------------
__global__ __launch_bounds__(256) void proj_kernel(
    const u16* __restrict__ xb, const u16* __restrict__ wb,
    const float* __restrict__ bq, const float* __restrict__ bk, const float* __restrict__ bv,
    u16* __restrict__ qh, u16* __restrict__ kh, u16* __restrict__ vt)
{
    const int z = blockIdx.z;
    const u16* A  = xb + (size_t)z * 4194304;
    const u16* B  = wb + (size_t)z * 1048576;
    const float* Bp = (z == 0) ? bq : (z == 1) ? bk : bv;
    u16* dst        = (z == 0) ? qh : (z == 1) ? kh : vt;

    const int m0 = blockIdx.y * 128;
    const int n0 = blockIdx.x * 128;
    const int tid  = threadIdx.x;
    const int wave = tid >> 6, lane = tid & 63;
    const int quad = lane >> 4, l15 = lane & 15;
    const int waveM = wave >> 1, waveN = wave & 1;

    // unpadded (required by global_load_lds lane mapping): 128 rows x 64 bf16
    __shared__ __align__(16) u16 As[128 * 64];
    __shared__ __align__(16) u16 Bs[128 * 64];

    floatx4 acc[4][4];
    for (int a = 0; a < 4; a++)
        for (int b = 0; b < 4; b++)
            acc[a][b] = floatx4{0.f, 0.f, 0.f, 0.f};

    const int lrow = lane >> 3, lcol = (lane & 7) * 8;   // within 8-row x 64-col slab

    for (int k0 = 0; k0 < KDIM; k0 += 64) {
        // each wave stages 32 rows of A and of B: 4 instrs each, 8 rows/instr
        for (int j = 0; j < 4; j++) {
            int r8 = wave * 32 + j * 8;
            gll16(A + (size_t)(m0 + r8 + lrow) * KDIM + k0 + lcol, &As[r8 * 64]);
        }
        for (int j = 0; j < 4; j++) {
            int r8 = wave * 32 + j * 8;
            gll16(B + (size_t)(n0 + r8 + lrow) * KDIM + k0 + lcol, &Bs[r8 * 64]);
        }
        __syncthreads();

        for (int ks = 0; ks < 2; ks++) {
            short8 af[4], bfg[4];
            for (int mb = 0; mb < 4; mb++)
                af[mb]  = *(const short8*)&As[(waveM * 64 + mb * 16 + l15) * 64 + ks * 32 + quad * 8];
            for (int nb = 0; nb < 4; nb++)
                bfg[nb] = *(const short8*)&Bs[(waveN * 64 + nb * 16 + l15) * 64 + ks * 32 + quad * 8];
            for (int mb = 0; mb < 4; mb++)
                for (int nb = 0; nb < 4; nb++)
                    acc[mb][nb] = __builtin_amdgcn_mfma_f32_16x16x32_bf16(af[mb], bfg[nb], acc[mb][nb], 0, 0, 0);
        }
        __syncthreads();
    }

    // epilogue: bias (+0.125 scale for Q: folds 1/sqrt(d) into the QK MFMA)
    const int row0 = m0 + waveM * 64;
    const int col0 = n0 + waveN * 64;
    const float scale = (z == 0) ? 0.125f : 1.0f;
    for (int nb = 0; nb < 4; nb++) {
        int col = col0 + nb * 16 + l15;
        float bias = Bp[col];
        int hh = col >> 6, dd = col & 63;
        for (int mb = 0; mb < 4; mb++) {
            for (int r = 0; r < 4; r++) {
                int row = row0 + mb * 16 + quad * 4 + r;    // C/D: row = quad*4+reg (m89)
                int nn = row >> 11, ss = row & 2047;
                u16 o = f2bf((acc[mb][nb][r] + bias) * scale);
                if (z == 2)
                    dst[((size_t)(nn * HEADS + hh) * DH + dd) * SEQ + ss] = o;  // V^T [n][h][d][t]
                else
                    dst[((size_t)(nn * HEADS + hh) * SEQ + ss) * DH + dd] = o;  // [n][h][s][d]
            }
        }
    }
}

// ---------------------------------------------------------------------------
// vmean[(n*H+h)*D + d] = mean over t of projected V (fallback for fully-masked rows)
// ---------------------------------------------------------------------------
__global__ __launch_bounds__(256) void vmean_kernel(const u16* __restrict__ vt,
                                                    float* __restrict__ vmean)
{
    const int row = blockIdx.x;                // (n*H + h)*D + d
    const u16* p = vt + (size_t)row * SEQ;
    const int tid = threadIdx.x;
    float s = 0.f;
    for (int i = tid; i < SEQ; i += 256) s += bf2f(p[i]);
    __shared__ float red[256];
    red[tid] = s;
    __syncthreads();
    for (int st = 128; st > 0; st >>= 1) {
        if (tid < st) red[tid] += red[tid + st];
        __syncthreads();
    }
    if (tid == 0) vmean[row] = red[0] * (1.f / (float)SEQ);
}

// ---------------------------------------------------------------------------
// Attention. Each workgroup: one (n,h), serially processes the complementary
// pair of 64-row Q tiles (sb, 31-sb) -> uniform 33 t-iterations per workgroup.
// S^T = K*Q^T trick: lane's score quad is consecutive in t -> packed 8B Ps
// writes; PV A-frag read stays ds_read_b128. Ps rows are wave-private ->
// no mid-barrier, just s_waitcnt lgkmcnt(0). K/V tiles register-prefetched.
// No max-subtraction (|score| < ~10, exp safe in fp32); l==0 rows -> vmean.
// ---------------------------------------------------------------------------
__global__ __launch_bounds__(256) void attn_kernel(
    const u16* __restrict__ qh, const u16* __restrict__ kh, const u16* __restrict__ vt,
    const int* __restrict__ pad, const float* __restrict__ vmean,
    float* __restrict__ out)
{
    const int nh = blockIdx.y;                 // n*H + h
    const int n = nh >> 4, h = nh & 15;
    const int tid  = threadIdx.x;
    const int wave = tid >> 6, lane = tid & 63;
    const int quad = lane >> 4, l15 = lane & 15;

    __shared__ __align__(16) u16 Ks[64 * 72];   // K tile [t][d]
    __shared__ __align__(16) u16 Vs[64 * 72];   // V^T tile [d][t]
    __shared__ __align__(16) u16 Ps[64 * 72];   // P [s][t], rows wave-private
    __shared__ int pads[SEQ];

    for (int i = tid; i < SEQ; i += 256) pads[i] = pad[n * SEQ + i];

    const u16* qbase = qh + (size_t)nh * SEQ * DH;
    const u16* kbase = kh + (size_t)nh * SEQ * DH;
    const u16* vbase = vt + (size_t)nh * DH * SEQ;

    short8 ones;
    for (int i = 0; i < 8; i++) ones[i] = (short)0x3F80;   // bf16(1.0)

    float vm[4];
    for (int nd = 0; nd < 4; nd++) vm[nd] = vmean[nh * DH + nd * 16 + l15];

    const int ldrow = (lane >> 3), ldcol = (lane & 7) * 8; // staging helper (64x64 tile, 8 rows/256-lane... 2 chunks/thread)

    for (int half = 0; half < 2; half++) {
        const int sb = (half == 0) ? blockIdx.x : (31 - blockIdx.x);
        const int s0 = sb * 64;
        const int nt = sb + 1;
        const int srow = s0 + wave * 16 + l15;             // this lane's score col (s)

        short8 qf[2];
        for (int ks = 0; ks < 2; ks++)
            qf[ks] = *(const short8*)(qbase + (size_t)srow * DH + ks * 32 + quad * 8);

        floatx4 oacc[4];
        for (int nd = 0; nd < 4; nd++) oacc[nd] = floatx4{0.f, 0.f, 0.f, 0.f};
        floatx4 lacc = floatx4{0.f, 0.f, 0.f, 0.f};

        // prefetch tile 0 into registers
        short8 rK[2], rV[2];
        {
            const int t0 = 0;
            for (int i = 0; i < 2; i++) {
                int idx = i * 256 + tid, row = idx >> 3, c = (idx & 7) * 8;
                rK[i] = *(const short8*)(kbase + (size_t)(t0 + row) * DH + c);
                rV[i] = *(const short8*)(vbase + (size_t)row * SEQ + t0 + c);
            }
        }

        for (int tb = 0; tb < nt; tb++) {
            __syncthreads();    // prior iter's (or prior half's / pads) LDS use done
            for (int i = 0; i < 2; i++) {
                int idx = i * 256 + tid, row = idx >> 3, c = (idx & 7) * 8;
                *(short8*)&Ks[row * 72 + c] = rK[i];
                *(short8*)&Vs[row * 72 + c] = rV[i];
            }
            __syncthreads();    // staging visible

            // prefetch next tile (global latency overlapped with compute below)
            if (tb + 1 < nt) {
                const int t0n = (tb + 1) * 64;
                for (int i = 0; i < 2; i++) {
                    int idx = i * 256 + tid, row = idx >> 3, c = (idx & 7) * 8;
                    rK[i] = *(const short8*)(kbase + (size_t)(t0n + row) * DH + c);
                    rV[i] = *(const short8*)(vbase + (size_t)row * SEQ + t0n + c);
                }
            }

            const int t0 = tb * 64;

            // S^T = K Q^T : D[m=t][n=s]; lane r-quad is consecutive t
            floatx4 sc[4];
            for (int nb = 0; nb < 4; nb++) sc[nb] = floatx4{0.f, 0.f, 0.f, 0.f};
            for (int ks = 0; ks < 2; ks++) {
                for (int nb = 0; nb < 4; nb++) {
                    short8 kf = *(const short8*)&Ks[(nb * 16 + l15) * 72 + ks * 32 + quad * 8];
                    sc[nb] = __builtin_amdgcn_mfma_f32_16x16x32_bf16(kf, qf[ks], sc[nb], 0, 0, 0);
                }
            }

            // mask + exp + packed 8B write into Ps[s][t]
            for (int nb = 0; nb < 4; nb++) {
                short4v pk;
                for (int r = 0; r < 4; r++) {
                    int t = t0 + nb * 16 + quad * 4 + r;
                    float p = (pads[t] != 0 && t <= srow) ? __expf(sc[nb][r]) : 0.f;
                    pk[r] = (short)f2bf(p);
                }
                *(short4v*)&Ps[(wave * 16 + l15) * 72 + nb * 16 + quad * 4] = pk;
            }
            asm volatile("s_waitcnt lgkmcnt(0)" ::: "memory");   // wave-local Ps RAW

            // O += P V ; l += P @ ones
            for (int ks = 0; ks < 2; ks++) {
                short8 pa = *(const short8*)&Ps[(wave * 16 + l15) * 72 + ks * 32 + quad * 8];
                for (int nd = 0; nd < 4; nd++) {
                    short8 vb = *(const short8*)&Vs[(nd * 16 + l15) * 72 + ks * 32 + quad * 8];
                    oacc[nd] = __builtin_amdgcn_mfma_f32_16x16x32_bf16(pa, vb, oacc[nd], 0, 0, 0);
                }
                lacc = __builtin_amdgcn_mfma_f32_16x16x32_bf16(pa, ones, lacc, 0, 0, 0);
            }
        }

        // epilogue: lane holds O[s = s0+wave*16+quad*4+r][d = nd*16+l15]
        for (int r = 0; r < 4; r++) {
            float l = lacc[r];
            int s = s0 + wave * 16 + quad * 4 + r;
            float* orow = out + (size_t)(n * SEQ + s) * EMB + h * DH;
            if (l > 0.f) {
                float inv = 1.f / l;
                for (int nd = 0; nd < 4; nd++) orow[nd * 16 + l15] = oacc[nd][r] * inv;
            } else {
                for (int nd = 0; nd < 4; nd++) orow[nd * 16 + l15] = vm[nd];
            }
        }
    }
}

extern "C" void kernel_launch(void* const* d_in, const int* in_sizes, int n_in,
                              void* d_out, int out_size, void* d_ws, size_t ws_size,
                              hipStream_t stream)
{
    const float* qin = (const float*)d_in[0];
    const float* kin = (const float*)d_in[1];
    const float* vin = (const float*)d_in[2];
    const int*   pad = (const int*)d_in[3];
    // d_in[4] = subsq_mask (tril) — implemented analytically as t <= s
    const float* Wq = (const float*)d_in[5];
    const float* bq = (const float*)d_in[6];
    const float* Wk = (const float*)d_in[7];
    const float* bk = (const float*)d_in[8];
    const float* Wv = (const float*)d_in[9];
    const float* bv = (const float*)d_in[10];
    float* out = (float*)d_out;

    const size_t per = (size_t)NBAT * HEADS * SEQ * DH;  // 4M elements
    u16* qh = (u16*)d_ws;
    u16* kh = qh + per;
    u16* vt = kh + per;
    float* vmean = (float*)(vt + per);                   // 2048 floats
    u16* xb = (u16*)(vmean + 2048);                      // 3 x 4M bf16
    u16* wb = xb + 3 * per;                              // 3 x 1M bf16

    cvt_kernel<<<dim3(512, 6), 256, 0, stream>>>(qin, kin, vin, Wq, Wk, Wv, xb, wb);
    proj_kernel<<<dim3(EMB / 128, NROW / 128, 3), 256, 0, stream>>>(
        xb, wb, bq, bk, bv, qh, kh, vt);
    vmean_kernel<<<dim3(NBAT * HEADS * DH), 256, 0, stream>>>(vt, vmean);
    attn_kernel<<<dim3(16, NBAT * HEADS), 256, 0, stream>>>(qh, kh, vt, pad, vmean, out);
}

// Round 4
// 230.942 us; speedup vs baseline: 1.3940x; 1.0511x over previous
//
#include <hip/hip_runtime.h>

#define HEADS 16
#define DH    64
#define EMB   1024
#define NBAT  2
#define SEQ   2048
#define KDIM  1024
#define NROW  (NBAT * SEQ)     // 4096 rows in projection GEMM

typedef __attribute__((ext_vector_type(8))) short short8;   // 8 bf16 MFMA A/B frag
typedef __attribute__((ext_vector_type(4))) short short4v;  // 4 bf16 (8B packed store)
typedef __attribute__((ext_vector_type(4))) float floatx4;  // MFMA C/D frag
typedef unsigned short u16;
typedef unsigned int   u32;
typedef unsigned long long u64;

__device__ __forceinline__ u16 f2bf(float x) {          // fp32 -> bf16 RNE
    u32 u = __builtin_bit_cast(u32, x);
    u += 0x7fffu + ((u >> 16) & 1u);
    return (u16)(u >> 16);
}
__device__ __forceinline__ float bf2f(u16 v) {
    return __builtin_bit_cast(float, ((u32)v) << 16);
}

// async global->LDS, 16B per lane; LDS dest is wave-uniform base + lane*16
__device__ __forceinline__ void gll16(const u16* g, u16* l) {
    __builtin_amdgcn_global_load_lds((const __attribute__((address_space(1))) u32*)g,
                                     (__attribute__((address_space(3))) u32*)l, 16, 0, 0);
}

// ---------------------------------------------------------------------------
// fp32 -> bf16 pre-convert of X (q,k,v: 4M elems each) and W (wq,wk,wv: 1M each)
// ---------------------------------------------------------------------------
__global__ __launch_bounds__(256) void cvt_kernel(
    const float* __restrict__ q, const float* __restrict__ k, const float* __restrict__ v,
    const float* __restrict__ wq, const float* __restrict__ wk, const float* __restrict__ wv,
    u16* __restrict__ xb, u16* __restrict__ wb)
{
    const int z = blockIdx.y;
    const float* src; u16* dst; int n;
    if (z < 3) { src = (z == 0) ? q : (z == 1) ? k : v;     dst = xb + (size_t)z * 4194304;       n = 4194304; }
    else       { src = (z == 3) ? wq : (z == 4) ? wk : wv;  dst = wb + (size_t)(z - 3) * 1048576; n = 1048576; }
    for (int i = (blockIdx.x * 256 + threadIdx.x) * 8; i < n; i += 512 * 256 * 8) {
        float4 a = *(const float4*)(src + i);
        float4 b = *(const float4*)(src + i + 4);
        short8 o;
        o[0] = (short)f2bf(a.x); o[1] = (short)f2bf(a.y); o[2] = (short)f2bf(a.z); o[3] = (short)f2bf(a.w);
        o[4] = (short)f2bf(b.x); o[5] = (short)f2bf(b.y); o[6] = (short)f2bf(b.z); o[7] = (short)f2bf(b.w);
        *(short8*)(dst + i) = o;
    }
}

// ---------------------------------------------------------------------------
// bf16 GEMM: out = Xb @ Wb^T (+bias). 128x128 tile, BK=64, global_load_lds.
// XCD swizzle: flat grid 768; blockIdx%8 -> XCD round-robin, XCD k owns
// row-groups g = k*12 .. k*12+11 (g = z*32+y), ALL 8 n-tiles each -> each
// A-tile fetched by exactly one XCD; W (2MB/z) stays L2-resident.
// z=0: Q*0.125 -> qh[n][h][s][d]; z=1: K -> kh[n][h][t][d]; z=2: V -> vt[n][h][d][t]
// (z=2 via LDS transpose for coalesced stores).
// ---------------------------------------------------------------------------
__global__ __launch_bounds__(256) void proj_kernel(
    const u16* __restrict__ xb, const u16* __restrict__ wb,
    const float* __restrict__ bq, const float* __restrict__ bk, const float* __restrict__ bv,
    u16* __restrict__ qh, u16* __restrict__ kh, u16* __restrict__ vt)
{
    const int f = blockIdx.x;
    const int xcd = f & 7, jj = f >> 3;          // jj 0..95
    const int g  = xcd * 12 + (jj >> 3);         // row-group 0..95 (z*32+y)
    const int nx = jj & 7;                       // n-tile 0..7
    const int z  = g >> 5, y = g & 31;

    const u16* A  = xb + (size_t)z * 4194304;
    const u16* B  = wb + (size_t)z * 1048576;
    const float* Bp = (z == 0) ? bq : (z == 1) ? bk : bv;
    u16* dst        = (z == 0) ? qh : (z == 1) ? kh : vt;

    const int m0 = y * 128;
    const int n0 = nx * 128;
    const int tid  = threadIdx.x;
    const int wave = tid >> 6, lane = tid & 63;
    const int quad = lane >> 4, l15 = lane & 15;
    const int waveM = wave >> 1, waveN = wave & 1;

    // single array so the epilogue transpose can alias the full 32KB
    __shared__ __align__(16) u16 smem[2 * 128 * 64];
    u16* As = smem;
    u16* Bs = smem + 128 * 64;

    floatx4 acc[4][4];
    for (int a = 0; a < 4; a++)
        for (int b = 0; b < 4; b++)
            acc[a][b] = floatx4{0.f, 0.f, 0.f, 0.f};

    const int lrow = lane >> 3, lcol = (lane & 7) * 8;   // 8-row x 64-col slab

    for (int k0 = 0; k0 < KDIM; k0 += 64) {
        for (int j = 0; j < 4; j++) {
            int r8 = wave * 32 + j * 8;
            gll16(A + (size_t)(m0 + r8 + lrow) * KDIM + k0 + lcol, &As[r8 * 64]);
        }
        for (int j = 0; j < 4; j++) {
            int r8 = wave * 32 + j * 8;
            gll16(B + (size_t)(n0 + r8 + lrow) * KDIM + k0 + lcol, &Bs[r8 * 64]);
        }
        __syncthreads();

        for (int ks = 0; ks < 2; ks++) {
            short8 af[4], bfg[4];
            for (int mb = 0; mb < 4; mb++)
                af[mb]  = *(const short8*)&As[(waveM * 64 + mb * 16 + l15) * 64 + ks * 32 + quad * 8];
            for (int nb = 0; nb < 4; nb++)
                bfg[nb] = *(const short8*)&Bs[(waveN * 64 + nb * 16 + l15) * 64 + ks * 32 + quad * 8];
            for (int mb = 0; mb < 4; mb++)
                for (int nb = 0; nb < 4; nb++)
                    acc[mb][nb] = __builtin_amdgcn_mfma_f32_16x16x32_bf16(af[mb], bfg[nb], acc[mb][nb], 0, 0, 0);
        }
        __syncthreads();
    }

    if (z != 2) {
        // direct scalar stores: [n][h][s][d]; 16 consecutive d per quad = 32B runs
        const int row0 = m0 + waveM * 64;
        const int col0 = n0 + waveN * 64;
        const float scale = (z == 0) ? 0.125f : 1.0f;   // fold 1/sqrt(d) into Q
        for (int nb = 0; nb < 4; nb++) {
            int col = col0 + nb * 16 + l15;
            float bias = Bp[col];
            int hh = col >> 6, dd = col & 63;
            for (int mb = 0; mb < 4; mb++) {
                for (int r = 0; r < 4; r++) {
                    int row = row0 + mb * 16 + quad * 4 + r;   // C/D: row = quad*4+reg
                    int nn = row >> 11, ss = row & 2047;
                    dst[((size_t)(nn * HEADS + hh) * SEQ + ss) * DH + dd] =
                        f2bf((acc[mb][nb][r] + bias) * scale);
                }
            }
        }
    } else {
        // V^T [n][h][d][t]: transpose 64-col half-tiles through LDS (stride 136
        // u16 -> bank step 4, 2-way aliasing = free), then coalesced 16B stores.
        // FIX(r4): write index must include waveM*64 (tile row, 0..127), else
        // waveM=1 rows clobber waveM=0 rows.
        const int nn  = m0 >> 11;
        const int ss0 = m0 & 2047;
        for (int p = 0; p < 2; p++) {
            if (waveN == p) {
                for (int nb = 0; nb < 4; nb++) {
                    int col_l = nb * 16 + l15;                   // d within head, 0..63
                    float bias = Bp[n0 + p * 64 + col_l];
                    for (int mb = 0; mb < 4; mb++) {
                        short4v pk;
                        for (int r = 0; r < 4; r++)
                            pk[r] = (short)f2bf(acc[mb][nb][r] + bias);
                        *(short4v*)&smem[col_l * 136 + waveM * 64 + mb * 16 + quad * 4] = pk;
                    }
                }
            }
            __syncthreads();
            const int hh = (n0 >> 6) + p;
            u16* drow = dst + ((size_t)(nn * HEADS + hh) * DH) * SEQ + ss0;
            for (int c2 = tid; c2 < 1024; c2 += 256) {
                int dl = c2 >> 4, tc = (c2 & 15) * 8;
                short8 vv = *(const short8*)&smem[dl * 136 + tc];
                *(short8*)(drow + (size_t)dl * SEQ + tc) = vv;
            }
            __syncthreads();
        }
    }
}

// ---------------------------------------------------------------------------
// vmean[(n*H+h)*D + d] = mean over t of projected V (fallback for fully-masked rows)
// ---------------------------------------------------------------------------
__global__ __launch_bounds__(256) void vmean_kernel(const u16* __restrict__ vt,
                                                    float* __restrict__ vmean)
{
    const int row = blockIdx.x;                // (n*H + h)*D + d
    const u16* p = vt + (size_t)row * SEQ;
    const int tid = threadIdx.x;
    float s = 0.f;
    for (int i = tid; i < SEQ; i += 256) s += bf2f(p[i]);
    __shared__ float red[256];
    red[tid] = s;
    __syncthreads();
    for (int st = 128; st > 0; st >>= 1) {
        if (tid < st) red[tid] += red[tid + st];
        __syncthreads();
    }
    if (tid == 0) vmean[row] = red[0] * (1.f / (float)SEQ);
}

// ---------------------------------------------------------------------------
// Attention. Flat grid 512; XCD swizzle: XCD k owns heads nh = 4k..4k+3, so
// each head's K/V (512KB) is L2-resident across its 16 blocks. Each block
// processes the complementary pair of 64-row Q tiles (pr, 31-pr) -> uniform
// 33 t-iterations. Double-buffered K/V tiles -> ONE barrier per t-iter.
// S^T = K*Q^T: lane's score quad consecutive in t -> packed 8B Ps writes;
// Ps rows wave-private (lgkmcnt(0) only). Pad mask = 64-bit ballot words,
// one LDS read per tile; causal compare only on the diagonal tile.
// No max-subtraction (|score| ~< 10); l==0 rows -> vmean.
// ---------------------------------------------------------------------------
__global__ __launch_bounds__(256) void attn_kernel(
    const u16* __restrict__ qh, const u16* __restrict__ kh, const u16* __restrict__ vt,
    const int* __restrict__ pad, const float* __restrict__ vmean,
    float* __restrict__ out)
{
    const int f = blockIdx.x;
    const int xcd = f & 7, jj = f >> 3;        // jj 0..63
    const int nh = xcd * 4 + (jj >> 4);
    const int pr = jj & 15;
    const int n = nh >> 4, h = nh & 15;
    const int tid  = threadIdx.x;
    const int wave = tid >> 6, lane = tid & 63;
    const int quad = lane >> 4, l15 = lane & 15;

    __shared__ __align__(16) u16 Ks[2][64 * 72];
    __shared__ __align__(16) u16 Vs[2][64 * 72];
    __shared__ __align__(16) u16 Ps[64 * 72];
    __shared__ u64 padb[32];

    // pad bitmask via wave ballots
    {
        const int* pp = pad + n * SEQ;
        for (int i = 0; i < 8; i++) {
            int seg = wave * 8 + i;
            u64 m = __ballot(pp[seg * 64 + lane] != 0);
            if (lane == 0) padb[seg] = m;
        }
    }

    const u16* qbase = qh + (size_t)nh * SEQ * DH;
    const u16* kbase = kh + (size_t)nh * SEQ * DH;
    const u16* vbase = vt + (size_t)nh * DH * SEQ;

    short8 ones;
    for (int i = 0; i < 8; i++) ones[i] = (short)0x3F80;   // bf16(1.0)
    float vm[4];
    for (int nd = 0; nd < 4; nd++) vm[nd] = vmean[nh * DH + nd * 16 + l15];

    for (int half = 0; half < 2; half++) {
        const int sb = half ? (31 - pr) : pr;
        const int s0 = sb * 64;
        const int nt = sb + 1;
        const int srow = s0 + wave * 16 + l15;

        short8 qf[2];
        for (int ks = 0; ks < 2; ks++)
            qf[ks] = *(const short8*)(qbase + (size_t)srow * DH + ks * 32 + quad * 8);

        floatx4 oacc[4], lacc;
        for (int nd = 0; nd < 4; nd++) oacc[nd] = floatx4{0.f, 0.f, 0.f, 0.f};
        lacc = floatx4{0.f, 0.f, 0.f, 0.f};

        // register prefetch of tile 0
        short8 rK[2], rV[2];
        for (int i = 0; i < 2; i++) {
            int idx = i * 256 + tid, row = idx >> 3, c = (idx & 7) * 8;
            rK[i] = *(const short8*)(kbase + (size_t)row * DH + c);
            rV[i] = *(const short8*)(vbase + (size_t)row * SEQ + c);
        }
        __syncthreads();   // prior half's buffer readers done; padb visible (half 0)

        for (int tb = 0; tb < nt; tb++) {
            const int cur = tb & 1;
            for (int i = 0; i < 2; i++) {
                int idx = i * 256 + tid, row = idx >> 3, c = (idx & 7) * 8;
                *(short8*)&Ks[cur][row * 72 + c] = rK[i];
                *(short8*)&Vs[cur][row * 72 + c] = rV[i];
            }
            if (tb + 1 < nt) {     // prefetch next tile (overlaps compute below)
                const int t0n = (tb + 1) * 64;
                for (int i = 0; i < 2; i++) {
                    int idx = i * 256 + tid, row = idx >> 3, c = (idx & 7) * 8;
                    rK[i] = *(const short8*)(kbase + (size_t)(t0n + row) * DH + c);
                    rV[i] = *(const short8*)(vbase + (size_t)row * SEQ + t0n + c);
                }
            }
            __syncthreads();       // single barrier per iteration

            const int t0 = tb * 64;
            const u64 w = padb[t0 >> 6];
            const bool diag = (tb == sb);

            // S^T = K Q^T : D[m=t][n=s]; lane r-quad consecutive in t
            floatx4 sc[4];
            for (int nb = 0; nb < 4; nb++) sc[nb] = floatx4{0.f, 0.f, 0.f, 0.f};
            for (int ks = 0; ks < 2; ks++)
                for (int nb = 0; nb < 4; nb++) {
                    short8 kf = *(const short8*)&Ks[cur][(nb * 16 + l15) * 72 + ks * 32 + quad * 8];
                    sc[nb] = __builtin_amdgcn_mfma_f32_16x16x32_bf16(kf, qf[ks], sc[nb], 0, 0, 0);
                }

            // mask + exp + packed 8B write into Ps[s][t]
            for (int nb = 0; nb < 4; nb++) {
                short4v pk;
                for (int r = 0; r < 4; r++) {
                    int sh = nb * 16 + quad * 4 + r;        // t - t0
                    bool ok = ((w >> sh) & 1ull) != 0;
                    if (diag) ok = ok && (t0 + sh <= srow);
                    float p = ok ? __expf(sc[nb][r]) : 0.f;
                    pk[r] = (short)f2bf(p);
                }
                *(short4v*)&Ps[(wave * 16 + l15) * 72 + nb * 16 + quad * 4] = pk;
            }
            asm volatile("s_waitcnt lgkmcnt(0)" ::: "memory");   // wave-local Ps RAW

            // O += P V ; l += P @ ones
            for (int ks = 0; ks < 2; ks++) {
                short8 pa = *(const short8*)&Ps[(wave * 16 + l15) * 72 + ks * 32 + quad * 8];
                for (int nd = 0; nd < 4; nd++) {
                    short8 vb = *(const short8*)&Vs[cur][(nd * 16 + l15) * 72 + ks * 32 + quad * 8];
                    oacc[nd] = __builtin_amdgcn_mfma_f32_16x16x32_bf16(pa, vb, oacc[nd], 0, 0, 0);
                }
                lacc = __builtin_amdgcn_mfma_f32_16x16x32_bf16(pa, ones, lacc, 0, 0, 0);
            }
        }

        // epilogue: lane holds O[s = s0+wave*16+quad*4+r][d = nd*16+l15]
        for (int r = 0; r < 4; r++) {
            float l = lacc[r];
            int s = s0 + wave * 16 + quad * 4 + r;
            float* orow = out + (size_t)(n * SEQ + s) * EMB + h * DH;
            if (l > 0.f) {
                float inv = 1.f / l;
                for (int nd = 0; nd < 4; nd++) orow[nd * 16 + l15] = oacc[nd][r] * inv;
            } else {
                for (int nd = 0; nd < 4; nd++) orow[nd * 16 + l15] = vm[nd];
            }
        }
    }
}

extern "C" void kernel_launch(void* const* d_in, const int* in_sizes, int n_in,
                              void* d_out, int out_size, void* d_ws, size_t ws_size,
                              hipStream_t stream)
{
    const float* qin = (const float*)d_in[0];
    const float* kin = (const float*)d_in[1];
    const float* vin = (const float*)d_in[2];
    const int*   pad = (const int*)d_in[3];
    // d_in[4] = subsq_mask (tril) — implemented analytically as t <= s
    const float* Wq = (const float*)d_in[5];
    const float* bq = (const float*)d_in[6];
    const float* Wk = (const float*)d_in[7];
    const float* bk = (const float*)d_in[8];
    const float* Wv = (const float*)d_in[9];
    const float* bv = (const float*)d_in[10];
    float* out = (float*)d_out;

    const size_t per = (size_t)NBAT * HEADS * SEQ * DH;  // 4M elements
    u16* qh = (u16*)d_ws;
    u16* kh = qh + per;
    u16* vt = kh + per;
    float* vmean = (float*)(vt + per);                   // 2048 floats
    u16* xb = (u16*)(vmean + 2048);                      // 3 x 4M bf16
    u16* wb = xb + 3 * per;                              // 3 x 1M bf16

    cvt_kernel<<<dim3(512, 6), 256, 0, stream>>>(qin, kin, vin, Wq, Wk, Wv, xb, wb);
    proj_kernel<<<dim3(768), 256, 0, stream>>>(xb, wb, bq, bk, bv, qh, kh, vt);
    vmean_kernel<<<dim3(NBAT * HEADS * DH), 256, 0, stream>>>(vt, vmean);
    attn_kernel<<<dim3(512), 256, 0, stream>>>(qh, kh, vt, pad, vmean, out);
}

// Round 5
// 216.411 us; speedup vs baseline: 1.4875x; 1.0671x over previous
//
#include <hip/hip_runtime.h>

#define HEADS 16
#define DH    64
#define EMB   1024
#define NBAT  2
#define SEQ   2048
#define KDIM  1024
#define NROW  (NBAT * SEQ)     // 4096 rows in projection GEMM

typedef __attribute__((ext_vector_type(8))) short short8;   // 8 bf16 MFMA A/B frag
typedef __attribute__((ext_vector_type(4))) short short4v;  // 4 bf16 (8B packed store)
typedef __attribute__((ext_vector_type(4))) float floatx4;  // MFMA C/D frag
typedef unsigned short u16;
typedef unsigned int   u32;
typedef unsigned long long u64;

__device__ __forceinline__ u16 f2bf(float x) {          // fp32 -> bf16 RNE
    u32 u = __builtin_bit_cast(u32, x);
    u += 0x7fffu + ((u >> 16) & 1u);
    return (u16)(u >> 16);
}
__device__ __forceinline__ float bf2f(u16 v) {
    return __builtin_bit_cast(float, ((u32)v) << 16);
}

// async global->LDS, 16B per lane; LDS dest is wave-uniform base + lane*16
__device__ __forceinline__ void gll16(const u16* g, u16* l) {
    __builtin_amdgcn_global_load_lds((const __attribute__((address_space(1))) u32*)g,
                                     (__attribute__((address_space(3))) u32*)l, 16, 0, 0);
}

// ---------------------------------------------------------------------------
// fp32 -> bf16 pre-convert of X (q,k,v: 4M elems each) and W (wq,wk,wv: 1M each)
// ---------------------------------------------------------------------------
__global__ __launch_bounds__(256) void cvt_kernel(
    const float* __restrict__ q, const float* __restrict__ k, const float* __restrict__ v,
    const float* __restrict__ wq, const float* __restrict__ wk, const float* __restrict__ wv,
    u16* __restrict__ xb, u16* __restrict__ wb)
{
    const int z = blockIdx.y;
    const float* src; u16* dst; int n;
    if (z < 3) { src = (z == 0) ? q : (z == 1) ? k : v;     dst = xb + (size_t)z * 4194304;       n = 4194304; }
    else       { src = (z == 3) ? wq : (z == 4) ? wk : wv;  dst = wb + (size_t)(z - 3) * 1048576; n = 1048576; }
    for (int i = (blockIdx.x * 256 + threadIdx.x) * 8; i < n; i += 512 * 256 * 8) {
        float4 a = *(const float4*)(src + i);
        float4 b = *(const float4*)(src + i + 4);
        short8 o;
        o[0] = (short)f2bf(a.x); o[1] = (short)f2bf(a.y); o[2] = (short)f2bf(a.z); o[3] = (short)f2bf(a.w);
        o[4] = (short)f2bf(b.x); o[5] = (short)f2bf(b.y); o[6] = (short)f2bf(b.z); o[7] = (short)f2bf(b.w);
        *(short8*)(dst + i) = o;
    }
}

// ---------------------------------------------------------------------------
// bf16 GEMM: out = Xb @ Wb^T (+bias). 128x128 tile, BK=64, global_load_lds,
// XOR-swizzled LDS: LDS chunk c of row r holds global chunk c^(r&7) ->
// frag ds_read_b128 banks balanced (8 lanes/bank-group) instead of 16-way.
// XCD swizzle: flat grid 768; XCD k owns row-groups g=k*12..k*12+11, all 8
// n-tiles each -> A fetched once; W L2-resident.
// z=0: Q*(0.125*log2e) -> qh (folds 1/sqrt(d) AND log2(e) for exp2 softmax);
// z=1: K -> kh[n][h][t][d]; z=2: V -> vt[n][h][d][t] (LDS-transposed stores).
// ---------------------------------------------------------------------------
__global__ __launch_bounds__(256) void proj_kernel(
    const u16* __restrict__ xb, const u16* __restrict__ wb,
    const float* __restrict__ bq, const float* __restrict__ bk, const float* __restrict__ bv,
    u16* __restrict__ qh, u16* __restrict__ kh, u16* __restrict__ vt)
{
    const int f = blockIdx.x;
    const int xcd = f & 7, jj = f >> 3;          // jj 0..95
    const int g  = xcd * 12 + (jj >> 3);         // row-group 0..95 (z*32+y)
    const int nx = jj & 7;                       // n-tile 0..7
    const int z  = g >> 5, y = g & 31;

    const u16* A  = xb + (size_t)z * 4194304;
    const u16* B  = wb + (size_t)z * 1048576;
    const float* Bp = (z == 0) ? bq : (z == 1) ? bk : bv;
    u16* dst        = (z == 0) ? qh : (z == 1) ? kh : vt;

    const int m0 = y * 128;
    const int n0 = nx * 128;
    const int tid  = threadIdx.x;
    const int wave = tid >> 6, lane = tid & 63;
    const int quad = lane >> 4, l15 = lane & 15;
    const int waveM = wave >> 1, waveN = wave & 1;
    const int sw = l15 & 7;                      // read-side swizzle key (row&7)

    // single array so the epilogue transpose can alias the full 32KB
    __shared__ __align__(16) u16 smem[2 * 128 * 64];
    u16* As = smem;
    u16* Bs = smem + 128 * 64;

    floatx4 acc[4][4];
    for (int a = 0; a < 4; a++)
        for (int b = 0; b < 4; b++)
            acc[a][b] = floatx4{0.f, 0.f, 0.f, 0.f};

    const int lrow = lane >> 3;                  // 0..7 within 8-row slab
    const int gcol = ((lane & 7) ^ lrow) * 8;    // XOR-swizzled source chunk

    for (int k0 = 0; k0 < KDIM; k0 += 64) {
        for (int j = 0; j < 4; j++) {
            int r8 = wave * 32 + j * 8;
            gll16(A + (size_t)(m0 + r8 + lrow) * KDIM + k0 + gcol, &As[r8 * 64]);
        }
        for (int j = 0; j < 4; j++) {
            int r8 = wave * 32 + j * 8;
            gll16(B + (size_t)(n0 + r8 + lrow) * KDIM + k0 + gcol, &Bs[r8 * 64]);
        }
        __syncthreads();

        for (int ks = 0; ks < 2; ks++) {
            short8 af[4], bfg[4];
            for (int mb = 0; mb < 4; mb++)
                af[mb]  = *(const short8*)&As[(waveM * 64 + mb * 16 + l15) * 64 + ((ks * 4 + quad) ^ sw) * 8];
            for (int nb = 0; nb < 4; nb++)
                bfg[nb] = *(const short8*)&Bs[(waveN * 64 + nb * 16 + l15) * 64 + ((ks * 4 + quad) ^ sw) * 8];
            for (int mb = 0; mb < 4; mb++)
                for (int nb = 0; nb < 4; nb++)
                    acc[mb][nb] = __builtin_amdgcn_mfma_f32_16x16x32_bf16(af[mb], bfg[nb], acc[mb][nb], 0, 0, 0);
        }
        __syncthreads();
    }

    if (z != 2) {
        // direct stores: [n][h][s][d]; 16 consecutive d per quad = 32B runs
        const int row0 = m0 + waveM * 64;
        const int col0 = n0 + waveN * 64;
        // z=0: fold 1/sqrt(d) * log2(e) so softmax uses bare v_exp_f32 (2^x)
        const float scale = (z == 0) ? 0.125f * 1.44269504f : 1.0f;
        for (int nb = 0; nb < 4; nb++) {
            int col = col0 + nb * 16 + l15;
            float bias = Bp[col];
            int hh = col >> 6, dd = col & 63;
            for (int mb = 0; mb < 4; mb++) {
                for (int r = 0; r < 4; r++) {
                    int row = row0 + mb * 16 + quad * 4 + r;   // C/D: row = quad*4+reg
                    int nn = row >> 11, ss = row & 2047;
                    dst[((size_t)(nn * HEADS + hh) * SEQ + ss) * DH + dd] =
                        f2bf((acc[mb][nb][r] + bias) * scale);
                }
            }
        }
    } else {
        // V^T [n][h][d][t]: transpose 64-col half-tiles through LDS (stride 136
        // u16 -> 2-way bank aliasing = free), then coalesced 16B stores.
        const int nn  = m0 >> 11;
        const int ss0 = m0 & 2047;
        for (int p = 0; p < 2; p++) {
            if (waveN == p) {
                for (int nb = 0; nb < 4; nb++) {
                    int col_l = nb * 16 + l15;                   // d within head, 0..63
                    float bias = Bp[n0 + p * 64 + col_l];
                    for (int mb = 0; mb < 4; mb++) {
                        short4v pk;
                        for (int r = 0; r < 4; r++)
                            pk[r] = (short)f2bf(acc[mb][nb][r] + bias);
                        *(short4v*)&smem[col_l * 136 + waveM * 64 + mb * 16 + quad * 4] = pk;
                    }
                }
            }
            __syncthreads();
            const int hh = (n0 >> 6) + p;
            u16* drow = dst + ((size_t)(nn * HEADS + hh) * DH) * SEQ + ss0;
            for (int c2 = tid; c2 < 1024; c2 += 256) {
                int dl = c2 >> 4, tc = (c2 & 15) * 8;
                short8 vv = *(const short8*)&smem[dl * 136 + tc];
                *(short8*)(drow + (size_t)dl * SEQ + tc) = vv;
            }
            __syncthreads();
        }
    }
}

// ---------------------------------------------------------------------------
// vmean[(n*H+h)*D + d] = mean over t of projected V (fallback for fully-masked rows)
// ---------------------------------------------------------------------------
__global__ __launch_bounds__(256) void vmean_kernel(const u16* __restrict__ vt,
                                                    float* __restrict__ vmean)
{
    const int row = blockIdx.x;                // (n*H + h)*D + d
    const u16* p = vt + (size_t)row * SEQ;
    const int tid = threadIdx.x;
    float s = 0.f;
    for (int i = tid; i < SEQ; i += 256) s += bf2f(p[i]);
    __shared__ float red[256];
    red[tid] = s;
    __syncthreads();
    for (int st = 128; st > 0; st >>= 1) {
        if (tid < st) red[tid] += red[tid + st];
        __syncthreads();
    }
    if (tid == 0) vmean[row] = red[0] * (1.f / (float)SEQ);
}

// ---------------------------------------------------------------------------
// Attention. Flat grid 512; XCD k owns heads 4k..4k+3 (K/V L2-resident).
// Block processes complementary Q-tile pair (pr, 31-pr) -> uniform 33 iters.
// K/V staged via XOR-swizzled global_load_lds into double buffers; next tile
// issued right after the single per-iter barrier -> full compute phase of
// slack before its drain. S^T = K*Q^T (packed Ps writes, wave-private rows).
// Softmax: scores pre-scaled by log2e -> bare exp2; no max-subtraction.
// Pad mask = ballot bitmask; causal only on diagonal tile; l==0 -> vmean.
// ---------------------------------------------------------------------------
__global__ __launch_bounds__(256) void attn_kernel(
    const u16* __restrict__ qh, const u16* __restrict__ kh, const u16* __restrict__ vt,
    const int* __restrict__ pad, const float* __restrict__ vmean,
    float* __restrict__ out)
{
    const int f = blockIdx.x;
    const int xcd = f & 7, jj = f >> 3;        // jj 0..63
    const int nh = xcd * 4 + (jj >> 4);
    const int pr = jj & 15;
    const int n = nh >> 4, h = nh & 15;
    const int tid  = threadIdx.x;
    const int wave = tid >> 6, lane = tid & 63;
    const int quad = lane >> 4, l15 = lane & 15;
    const int sw = l15 & 7;                    // frag-read swizzle key

    __shared__ __align__(16) u16 Ks[2][64 * 64];   // [t][d], XOR-swizzled chunks
    __shared__ __align__(16) u16 Vs[2][64 * 64];   // [d][t], XOR-swizzled chunks
    __shared__ __align__(16) u16 Ps[64 * 72];      // P [s][t], wave-private rows
    __shared__ u64 padb[32];

    // pad bitmask via wave ballots
    {
        const int* pp = pad + n * SEQ;
        for (int i = 0; i < 8; i++) {
            int seg = wave * 8 + i;
            u64 m = __ballot(pp[seg * 64 + lane] != 0);
            if (lane == 0) padb[seg] = m;
        }
    }

    const u16* qbase = qh + (size_t)nh * SEQ * DH;
    const u16* kbase = kh + (size_t)nh * SEQ * DH;
    const u16* vbase = vt + (size_t)nh * DH * SEQ;

    short8 ones;
    for (int i = 0; i < 8; i++) ones[i] = (short)0x3F80;   // bf16(1.0)
    float vm[4];
    for (int nd = 0; nd < 4; nd++) vm[nd] = vmean[nh * DH + nd * 16 + l15];

    const int lrow = lane >> 3;                 // 0..7 within 8-row slab
    const int gcol = ((lane & 7) ^ lrow) * 8;   // XOR-swizzled source chunk

    for (int half = 0; half < 2; half++) {
        const int sb = half ? (31 - pr) : pr;
        const int s0 = sb * 64;
        const int nt = sb + 1;
        const int srow = s0 + wave * 16 + l15;

        short8 qf[2];
        for (int ks = 0; ks < 2; ks++)
            qf[ks] = *(const short8*)(qbase + (size_t)srow * DH + ks * 32 + quad * 8);

        floatx4 oacc[4], lacc;
        for (int nd = 0; nd < 4; nd++) oacc[nd] = floatx4{0.f, 0.f, 0.f, 0.f};
        lacc = floatx4{0.f, 0.f, 0.f, 0.f};

        __syncthreads();   // half 0: padb visible; half 1: prev half's buffer reads done

        // stage tile 0 into buffer 0 (wave stages rows wave*16..wave*16+15)
        for (int j = 0; j < 2; j++) {
            int r8 = wave * 16 + j * 8;
            gll16(kbase + (size_t)(r8 + lrow) * DH + gcol, &Ks[0][r8 * 64]);
            gll16(vbase + (size_t)(r8 + lrow) * SEQ + gcol, &Vs[0][r8 * 64]);
        }

        for (int tb = 0; tb < nt; tb++) {
            const int cur = tb & 1;
            __syncthreads();       // drains own gll16s (issued a full iter ago) + buffer reuse

            if (tb + 1 < nt) {     // async prefetch of next tile into the other buffer
                const int t0n = (tb + 1) * 64;
                for (int j = 0; j < 2; j++) {
                    int r8 = wave * 16 + j * 8;
                    gll16(kbase + (size_t)(t0n + r8 + lrow) * DH + gcol, &Ks[1 - cur][r8 * 64]);
                    gll16(vbase + (size_t)(r8 + lrow) * SEQ + t0n + gcol, &Vs[1 - cur][r8 * 64]);
                }
            }

            const int t0 = tb * 64;
            const u64 w = padb[t0 >> 6];
            const bool diag = (tb == sb);

            // S^T = K Q^T : D[m=t][n=s]; lane r-quad consecutive in t
            floatx4 sc[4];
            for (int nb = 0; nb < 4; nb++) sc[nb] = floatx4{0.f, 0.f, 0.f, 0.f};
            for (int ks = 0; ks < 2; ks++)
                for (int nb = 0; nb < 4; nb++) {
                    short8 kf = *(const short8*)&Ks[cur][(nb * 16 + l15) * 64 + ((ks * 4 + quad) ^ sw) * 8];
                    sc[nb] = __builtin_amdgcn_mfma_f32_16x16x32_bf16(kf, qf[ks], sc[nb], 0, 0, 0);
                }

            // mask + exp2 + packed 8B write into Ps[s][t]
            for (int nb = 0; nb < 4; nb++) {
                short4v pk;
                for (int r = 0; r < 4; r++) {
                    int sh = nb * 16 + quad * 4 + r;        // t - t0
                    bool ok = ((w >> sh) & 1ull) != 0;
                    if (diag) ok = ok && (t0 + sh <= srow);
                    float p = ok ? __builtin_amdgcn_exp2f(sc[nb][r]) : 0.f;
                    pk[r] = (short)f2bf(p);
                }
                *(short4v*)&Ps[(wave * 16 + l15) * 72 + nb * 16 + quad * 4] = pk;
            }
            asm volatile("s_waitcnt lgkmcnt(0)" ::: "memory");   // wave-local Ps RAW

            // O += P V ; l += P @ ones
            for (int ks = 0; ks < 2; ks++) {
                short8 pa = *(const short8*)&Ps[(wave * 16 + l15) * 72 + ks * 32 + quad * 8];
                for (int nd = 0; nd < 4; nd++) {
                    short8 vb = *(const short8*)&Vs[cur][(nd * 16 + l15) * 64 + ((ks * 4 + quad) ^ sw) * 8];
                    oacc[nd] = __builtin_amdgcn_mfma_f32_16x16x32_bf16(pa, vb, oacc[nd], 0, 0, 0);
                }
                lacc = __builtin_amdgcn_mfma_f32_16x16x32_bf16(pa, ones, lacc, 0, 0, 0);
            }
        }

        // epilogue: lane holds O[s = s0+wave*16+quad*4+r][d = nd*16+l15]
        for (int r = 0; r < 4; r++) {
            float l = lacc[r];
            int s = s0 + wave * 16 + quad * 4 + r;
            float* orow = out + (size_t)(n * SEQ + s) * EMB + h * DH;
            if (l > 0.f) {
                float inv = 1.f / l;
                for (int nd = 0; nd < 4; nd++) orow[nd * 16 + l15] = oacc[nd][r] * inv;
            } else {
                for (int nd = 0; nd < 4; nd++) orow[nd * 16 + l15] = vm[nd];
            }
        }
    }
}

extern "C" void kernel_launch(void* const* d_in, const int* in_sizes, int n_in,
                              void* d_out, int out_size, void* d_ws, size_t ws_size,
                              hipStream_t stream)
{
    const float* qin = (const float*)d_in[0];
    const float* kin = (const float*)d_in[1];
    const float* vin = (const float*)d_in[2];
    const int*   pad = (const int*)d_in[3];
    // d_in[4] = subsq_mask (tril) — implemented analytically as t <= s
    const float* Wq = (const float*)d_in[5];
    const float* bq = (const float*)d_in[6];
    const float* Wk = (const float*)d_in[7];
    const float* bk = (const float*)d_in[8];
    const float* Wv = (const float*)d_in[9];
    const float* bv = (const float*)d_in[10];
    float* out = (float*)d_out;

    const size_t per = (size_t)NBAT * HEADS * SEQ * DH;  // 4M elements
    u16* qh = (u16*)d_ws;
    u16* kh = qh + per;
    u16* vt = kh + per;
    float* vmean = (float*)(vt + per);                   // 2048 floats
    u16* xb = (u16*)(vmean + 2048);                      // 3 x 4M bf16
    u16* wb = xb + 3 * per;                              // 3 x 1M bf16

    cvt_kernel<<<dim3(512, 6), 256, 0, stream>>>(qin, kin, vin, Wq, Wk, Wv, xb, wb);
    proj_kernel<<<dim3(768), 256, 0, stream>>>(xb, wb, bq, bk, bv, qh, kh, vt);
    vmean_kernel<<<dim3(NBAT * HEADS * DH), 256, 0, stream>>>(vt, vmean);
    attn_kernel<<<dim3(512), 256, 0, stream>>>(qh, kh, vt, pad, vmean, out);
}